// Round 1
// baseline (10002.352 us; speedup 1.0000x reference)
//
#include <hip/hip_runtime.h>

// Problem constants
#define NWIN 64      // windows per batch element
#define TW   32      // tokens per window
#define NFEAT 16
#define HID  64      // LSTM hidden per direction
#define EMB  128     // 2*HID

// ---------------- Kernel 1: fused per-window  ----------------
// block = 512 threads, grid = B*NW = 16384 blocks.
// LDS float offsets (stride 136 for [32][128] row-major buffers -> 2-way max
// conflicts; stride 33 for [128][32] transposed buffers -> conflict-free)
#define OFF_XS 0        // x window: 32*16 = 512
#define OFF_A  512      // lo[32][136]  ->  s[128][33]      (4352)
#define OFF_B  4864     // q[32][136]   ->  o[32][136]      (4352)
#define OFF_C  9216     // kT[128][33]  ->  r1[32][136]     (4352)
#define OFF_G  13568    // gate buffer 512
#define OFF_H  14080    // h state 128
#define SMEM_FLOATS 14208   // 56832 bytes

__device__ __forceinline__ float sigmoidf_(float x) { return 1.f / (1.f + expf(-x)); }

__global__ __launch_bounds__(512)
void fused_window_kernel(const float* __restrict__ x,
    const float* __restrict__ w_ih_f, const float* __restrict__ w_hh_f,
    const float* __restrict__ b_ih_f, const float* __restrict__ b_hh_f,
    const float* __restrict__ w_ih_b, const float* __restrict__ w_hh_b,
    const float* __restrict__ b_ih_b, const float* __restrict__ b_hh_b,
    const float* __restrict__ sa_in_w, const float* __restrict__ sa_in_b,
    const float* __restrict__ sa_out_w, const float* __restrict__ sa_out_b,
    const float* __restrict__ proj_w, const float* __restrict__ proj_b,
    float* __restrict__ pooled)
{
    __shared__ float sm[SMEM_FLOATS];
    const int tid = threadIdx.x;
    const int blk = blockIdx.x;
    const int bb = blk >> 6;       // batch index
    const int wi = blk & 63;       // window index

    // ---- stage x window into LDS (32 tokens x 16 feats = 512 floats) ----
    {
        const float* xsrc = x + ((size_t)bb * 2048 + wi * 32) * 16;
        sm[OFF_XS + tid] = xsrc[tid];
        if (tid < 128) sm[OFF_H + tid] = 0.f;
    }
    __syncthreads();

    // ---- BiLSTM: thread = dir*256 + gate ----
    {
        const int dir = tid >> 8;       // 0 fwd, 1 bwd
        const int gg  = tid & 255;      // gate index 0..255
        const float* wih_p = (dir ? w_ih_b : w_ih_f) + gg * 16;
        const float* whh_p = (dir ? w_hh_b : w_hh_f) + gg * 64;
        float wih[16];
        #pragma unroll
        for (int i = 0; i < 4; ++i) {
            float4 v4 = ((const float4*)wih_p)[i];
            wih[4*i] = v4.x; wih[4*i+1] = v4.y; wih[4*i+2] = v4.z; wih[4*i+3] = v4.w;
        }
        float whh[64];
        #pragma unroll
        for (int i = 0; i < 16; ++i) {
            float4 v4 = ((const float4*)whh_p)[i];
            whh[4*i] = v4.x; whh[4*i+1] = v4.y; whh[4*i+2] = v4.z; whh[4*i+3] = v4.w;
        }
        const float bias = dir ? (b_ih_b[gg] + b_hh_b[gg]) : (b_ih_f[gg] + b_hh_f[gg]);
        float c = 0.f;
        const float* hbase = &sm[OFF_H + dir * 64];

        for (int step = 0; step < 32; ++step) {
            const int t = dir ? (31 - step) : step;
            // gate pre-activation: xp(t) + W_hh h
            float acc = bias;
            const float* xrow = &sm[OFF_XS + t * 16];
            #pragma unroll
            for (int f = 0; f < 16; ++f) acc += xrow[f] * wih[f];
            #pragma unroll
            for (int k = 0; k < 64; ++k) acc += hbase[k] * whh[k];
            sm[OFF_G + tid] = acc;
            __syncthreads();
            if (gg < 64) {
                const int u = gg;
                const int gb = OFF_G + dir * 256;
                float ig = sigmoidf_(sm[gb + u]);
                float fg = sigmoidf_(sm[gb + 64 + u]);
                float gc = tanhf(sm[gb + 128 + u]);
                float og = sigmoidf_(sm[gb + 192 + u]);
                c = fg * c + ig * gc;
                const float h = og * tanhf(c);
                sm[OFF_H + dir * 64 + u] = h;
                sm[OFF_A + t * 136 + dir * 64 + u] = h;   // lo[t][dir*64+u]
            }
            __syncthreads();
        }
    }
    // lo complete in bufA.

    const int g = tid >> 5;   // 0..15 : e-group
    const int t = tid & 31;   // token / row
    float accv[8];            // v kept in registers across phases

    // ---- QKV projections: q->B (row-major), kT->C (transposed), v->regs ----
    {
        float accq[8], acck[8];
        #pragma unroll
        for (int ii = 0; ii < 8; ++ii) { accq[ii] = 0.f; acck[ii] = 0.f; accv[ii] = 0.f; }
        for (int j0 = 0; j0 < 128; j0 += 32) {
            float4 lor[8];
            const float4* lrow = (const float4*)&sm[OFF_A + t * 136 + j0];
            #pragma unroll
            for (int jj = 0; jj < 8; ++jj) lor[jj] = lrow[jj];
            #pragma unroll
            for (int ii = 0; ii < 8; ++ii) {
                const int e = g + 16 * ii;
                const float4* wq = (const float4*)(sa_in_w + (size_t)e * 128 + j0);
                const float4* wk = (const float4*)(sa_in_w + (size_t)(128 + e) * 128 + j0);
                const float4* wv = (const float4*)(sa_in_w + (size_t)(256 + e) * 128 + j0);
                #pragma unroll
                for (int jj = 0; jj < 8; ++jj) {
                    const float4 a = lor[jj];
                    const float4 q4 = wq[jj];
                    accq[ii] += a.x*q4.x + a.y*q4.y + a.z*q4.z + a.w*q4.w;
                    const float4 k4 = wk[jj];
                    acck[ii] += a.x*k4.x + a.y*k4.y + a.z*k4.z + a.w*k4.w;
                    const float4 v4 = wv[jj];
                    accv[ii] += a.x*v4.x + a.y*v4.y + a.z*v4.z + a.w*v4.w;
                }
            }
        }
        #pragma unroll
        for (int ii = 0; ii < 8; ++ii) {
            const int e = g + 16 * ii;
            sm[OFF_B + t * 136 + e] = accq[ii] + sa_in_b[e];          // q[t][e]
            sm[OFF_C + e * 33 + t]  = acck[ii] + sa_in_b[128 + e];    // kT[e][t]
            accv[ii] += sa_in_b[256 + e];                              // v[t][e] in reg
        }
    }
    __syncthreads();

    // ---- scores: s[h][qt][kt] = (q . k) / sqrt(32)  -> bufA ----
    {
        const float scale = 0.17677669529663687f;  // 1/sqrt(32)
        #pragma unroll
        for (int i = 0; i < 8; ++i) {
            const int p = tid + 512 * i;
            const int h = p >> 10, qt = (p >> 5) & 31, kt = p & 31;
            const float* qrow = &sm[OFF_B + qt * 136 + h * 32];
            const float* kcol = &sm[OFF_C + (h * 32) * 33 + kt];
            float acc = 0.f;
            #pragma unroll
            for (int d = 0; d < 32; ++d) acc += qrow[d] * kcol[d * 33];
            sm[OFF_A + (h * 32 + qt) * 33 + kt] = acc * scale;
        }
    }
    __syncthreads();

    // ---- softmax over kt (128 rows, one thread each) ----
    if (tid < 128) {
        float* row = &sm[OFF_A + tid * 33];
        float m = row[0];
        #pragma unroll
        for (int d = 1; d < 32; ++d) m = fmaxf(m, row[d]);
        float ssum = 0.f;
        #pragma unroll
        for (int d = 0; d < 32; ++d) { const float e2 = expf(row[d] - m); row[d] = e2; ssum += e2; }
        const float inv = 1.f / ssum;
        #pragma unroll
        for (int d = 0; d < 32; ++d) row[d] *= inv;
    }
    __syncthreads();

    // ---- o = A . V (V broadcast from registers via shfl within 32-lane group) ----
    {
        float oacc[8];
        #pragma unroll
        for (int ii = 0; ii < 8; ++ii) {
            const int e = g + 16 * ii;
            const int h = e >> 5;
            const float* srow = &sm[OFF_A + (h * 32 + t) * 33];
            float acc = 0.f;
            #pragma unroll 8
            for (int kt = 0; kt < 32; ++kt) {
                const float vb = __shfl(accv[ii], kt, 32);   // v[kt][e]
                acc += srow[kt] * vb;
            }
            oacc[ii] = acc;
        }
        #pragma unroll
        for (int ii = 0; ii < 8; ++ii)
            sm[OFF_B + t * 136 + (g + 16 * ii)] = oacc[ii];   // o[t][e] over q's space
    }
    __syncthreads();

    // ---- attention out-proj: r1 = o @ sa_out_w^T + b  -> bufC ----
    {
        float acc[8];
        #pragma unroll
        for (int ii = 0; ii < 8; ++ii) acc[ii] = 0.f;
        for (int j0 = 0; j0 < 128; j0 += 32) {
            float4 lor[8];
            const float4* lrow = (const float4*)&sm[OFF_B + t * 136 + j0];
            #pragma unroll
            for (int jj = 0; jj < 8; ++jj) lor[jj] = lrow[jj];
            #pragma unroll
            for (int ii = 0; ii < 8; ++ii) {
                const int e = g + 16 * ii;
                const float4* wr = (const float4*)(sa_out_w + (size_t)e * 128 + j0);
                #pragma unroll
                for (int jj = 0; jj < 8; ++jj) {
                    const float4 a = lor[jj]; const float4 w4 = wr[jj];
                    acc[ii] += a.x*w4.x + a.y*w4.y + a.z*w4.z + a.w*w4.w;
                }
            }
        }
        #pragma unroll
        for (int ii = 0; ii < 8; ++ii) {
            const int e = g + 16 * ii;
            sm[OFF_C + t * 136 + e] = acc[ii] + sa_out_b[e];
        }
    }
    __syncthreads();

    // ---- final proj + mean-pool over t ----
    {
        float acc[8];
        #pragma unroll
        for (int ii = 0; ii < 8; ++ii) acc[ii] = 0.f;
        for (int j0 = 0; j0 < 128; j0 += 32) {
            float4 lor[8];
            const float4* lrow = (const float4*)&sm[OFF_C + t * 136 + j0];
            #pragma unroll
            for (int jj = 0; jj < 8; ++jj) lor[jj] = lrow[jj];
            #pragma unroll
            for (int ii = 0; ii < 8; ++ii) {
                const int e = g + 16 * ii;
                const float4* wr = (const float4*)(proj_w + (size_t)e * 128 + j0);
                #pragma unroll
                for (int jj = 0; jj < 8; ++jj) {
                    const float4 a = lor[jj]; const float4 w4 = wr[jj];
                    acc[ii] += a.x*w4.x + a.y*w4.y + a.z*w4.z + a.w*w4.w;
                }
            }
        }
        #pragma unroll
        for (int ii = 0; ii < 8; ++ii) {
            const int e = g + 16 * ii;
            float val = acc[ii] + proj_b[e];
            val += __shfl_down(val, 16, 32);
            val += __shfl_down(val, 8, 32);
            val += __shfl_down(val, 4, 32);
            val += __shfl_down(val, 2, 32);
            val += __shfl_down(val, 1, 32);
            if (t == 0)
                pooled[((size_t)(bb * 64 + wi)) * 128 + e] = val * 0.03125f;
        }
    }
}

// ---------------- Kernel 2: cross-attention + layernorm ----------------
// block = 128 threads, grid = 64 (ci) * 256 (b) = 16384
__global__ __launch_bounds__(128)
void cross_attn_kernel(const float* __restrict__ pooled,
    const float* __restrict__ ca_in_w, const float* __restrict__ ca_in_b,
    const float* __restrict__ ca_out_w, const float* __restrict__ ca_out_b,
    const float* __restrict__ ln_g, const float* __restrict__ ln_b,
    float* __restrict__ seq)
{
    const int blk = blockIdx.x;
    const int ci = blk >> 8;     // window, 0..63  (256 consecutive blocks share weights)
    const int bb = blk & 255;    // batch
    const int tid = threadIdx.x; // 0..127
    __shared__ float cen[128], ctx[512], qsh[128], ksh[512], vsh[512], osh[128];
    __shared__ float att[16], red[2];

    const int left  = (ci - 2 > 0) ? ci - 2 : 0;
    const int right = (ci + 3 < 64) ? ci + 3 : 64;
    const int nc = right - left - 1;   // 2..4 neighbors excluding self

    cen[tid] = pooled[((size_t)bb * 64 + ci) * 128 + tid];
    for (int n2 = 0; n2 < nc; ++n2) {
        int idx = left + n2;
        if (idx >= ci) idx++;
        ctx[n2 * 128 + tid] = pooled[((size_t)bb * 64 + idx) * 128 + tid];
    }
    __syncthreads();

    const float* Wi = ca_in_w + (size_t)ci * 384 * 128;
    const float* bi = ca_in_b + ci * 384;
    const int e = tid;
    // q projection (center token)
    {
        const float4* wr = (const float4*)(Wi + (size_t)e * 128);
        const float4* cr = (const float4*)cen;
        float acc = bi[e];
        #pragma unroll 8
        for (int j = 0; j < 32; ++j) {
            const float4 a = cr[j], w4 = wr[j];
            acc += a.x*w4.x + a.y*w4.y + a.z*w4.z + a.w*w4.w;
        }
        qsh[e] = acc;
    }
    // k, v projections for each neighbor
    for (int n2 = 0; n2 < nc; ++n2) {
        const float4* xr = (const float4*)&ctx[n2 * 128];
        const float4* wk = (const float4*)(Wi + (size_t)(128 + e) * 128);
        const float4* wv = (const float4*)(Wi + (size_t)(256 + e) * 128);
        float acck = bi[128 + e], accv = bi[256 + e];
        #pragma unroll 8
        for (int j = 0; j < 32; ++j) {
            const float4 a = xr[j];
            const float4 k4 = wk[j]; acck += a.x*k4.x + a.y*k4.y + a.z*k4.z + a.w*k4.w;
            const float4 v4 = wv[j]; accv += a.x*v4.x + a.y*v4.y + a.z*v4.z + a.w*v4.w;
        }
        ksh[n2 * 128 + e] = acck; vsh[n2 * 128 + e] = accv;
    }
    __syncthreads();

    // scores + softmax (one thread per head)
    if (tid < 4) {
        const int h = tid;
        float s[4];
        float m = -1e30f;
        for (int n2 = 0; n2 < nc; ++n2) {
            float acc = 0.f;
            #pragma unroll
            for (int d = 0; d < 32; ++d) acc += qsh[h * 32 + d] * ksh[n2 * 128 + h * 32 + d];
            s[n2] = acc * 0.17677669529663687f;
            m = fmaxf(m, s[n2]);
        }
        float ssum = 0.f;
        for (int n2 = 0; n2 < nc; ++n2) { s[n2] = expf(s[n2] - m); ssum += s[n2]; }
        const float inv = 1.f / ssum;
        for (int n2 = 0; n2 < nc; ++n2) att[h * 4 + n2] = s[n2] * inv;
    }
    __syncthreads();

    {
        const int h = e >> 5;
        float oacc = 0.f;
        for (int n2 = 0; n2 < nc; ++n2) oacc += att[h * 4 + n2] * vsh[n2 * 128 + e];
        osh[e] = oacc;
    }
    __syncthreads();

    float res;
    {
        const float4* wr = (const float4*)(ca_out_w + (size_t)ci * 128 * 128 + (size_t)e * 128);
        const float4* orow = (const float4*)osh;
        float acc = ca_out_b[ci * 128 + e];
        #pragma unroll 8
        for (int j = 0; j < 32; ++j) {
            const float4 a = orow[j], w4 = wr[j];
            acc += a.x*w4.x + a.y*w4.y + a.z*w4.z + a.w*w4.w;
        }
        res = acc + cen[e];   // residual
    }
    // layernorm over 128
    const int lane = tid & 63, wid = tid >> 6;
    float sum = res;
    #pragma unroll
    for (int off = 32; off > 0; off >>= 1) sum += __shfl_down(sum, off, 64);
    if (lane == 0) red[wid] = sum;
    __syncthreads();
    const float mean = (red[0] + red[1]) * (1.f / 128.f);
    const float dv = res - mean;
    __syncthreads();
    float s2 = dv * dv;
    #pragma unroll
    for (int off = 32; off > 0; off >>= 1) s2 += __shfl_down(s2, off, 64);
    if (lane == 0) red[wid] = s2;
    __syncthreads();
    const float var = (red[0] + red[1]) * (1.f / 128.f);
    const float y = dv * rsqrtf(var + 1e-5f) * ln_g[ci * 128 + e] + ln_b[ci * 128 + e];
    seq[((size_t)bb * 64 + ci) * 128 + e] = y;
}

// ---------------- Kernel 3: final MLP head ----------------
// block = 256 threads, grid = 256 (one per batch row)
__global__ __launch_bounds__(256)
void head_kernel(const float* __restrict__ seq,
    const float* __restrict__ fd1_w, const float* __restrict__ fd1_b,
    const float* __restrict__ fd2_w, const float* __restrict__ fd2_b,
    float* __restrict__ out)
{
    const int bb = blockIdx.x;
    const int tid = threadIdx.x;
    const int j = tid >> 2, part = tid & 3;   // j: output unit 0..63, part: k-split
    __shared__ float red[256];
    __shared__ float h1[64];

    float acc = 0.f;
    const float4* wr = (const float4*)(fd1_w + (size_t)j * 8192 + part * 2048);
    const float4* sr = (const float4*)(seq + (size_t)bb * 8192 + part * 2048);
    #pragma unroll 4
    for (int i = 0; i < 512; ++i) {
        const float4 a = sr[i], w4 = wr[i];
        acc += a.x*w4.x + a.y*w4.y + a.z*w4.z + a.w*w4.w;
    }
    red[tid] = acc;
    __syncthreads();
    if (tid < 64) {
        const float s = red[tid * 4] + red[tid * 4 + 1] + red[tid * 4 + 2] + red[tid * 4 + 3]
                        + fd1_b[tid];
        h1[tid] = fmaxf(s, 0.f);
    }
    __syncthreads();
    if (tid < 5) {
        float acc2 = fd2_b[tid];
        const float* w2 = fd2_w + tid * 64;
        #pragma unroll
        for (int k = 0; k < 64; ++k) acc2 += h1[k] * w2[k];
        out[bb * 5 + tid] = acc2;
    }
}

extern "C" void kernel_launch(void* const* d_in, const int* in_sizes, int n_in,
                              void* d_out, int out_size, void* d_ws, size_t ws_size,
                              hipStream_t stream) {
    const float* x        = (const float*)d_in[0];
    const float* w_ih_f   = (const float*)d_in[1];
    const float* w_hh_f   = (const float*)d_in[2];
    const float* b_ih_f   = (const float*)d_in[3];
    const float* b_hh_f   = (const float*)d_in[4];
    const float* w_ih_b   = (const float*)d_in[5];
    const float* w_hh_b   = (const float*)d_in[6];
    const float* b_ih_b   = (const float*)d_in[7];
    const float* b_hh_b   = (const float*)d_in[8];
    const float* sa_in_w  = (const float*)d_in[9];
    const float* sa_in_b  = (const float*)d_in[10];
    const float* sa_out_w = (const float*)d_in[11];
    const float* sa_out_b = (const float*)d_in[12];
    const float* proj_w   = (const float*)d_in[13];
    const float* proj_b   = (const float*)d_in[14];
    const float* ca_in_w  = (const float*)d_in[15];
    const float* ca_in_b  = (const float*)d_in[16];
    const float* ca_out_w = (const float*)d_in[17];
    const float* ca_out_b = (const float*)d_in[18];
    const float* ln_g     = (const float*)d_in[19];
    const float* ln_b     = (const float*)d_in[20];
    const float* fd1_w    = (const float*)d_in[21];
    const float* fd1_b    = (const float*)d_in[22];
    const float* fd2_w    = (const float*)d_in[23];
    const float* fd2_b    = (const float*)d_in[24];

    float* pooled = (float*)d_ws;                       // 256*64*128 floats = 8 MB
    float* seq    = pooled + (size_t)256 * 64 * 128;    // 256*64*128 floats = 8 MB
    float* outp   = (float*)d_out;

    fused_window_kernel<<<dim3(16384), dim3(512), 0, stream>>>(
        x, w_ih_f, w_hh_f, b_ih_f, b_hh_f, w_ih_b, w_hh_b, b_ih_b, b_hh_b,
        sa_in_w, sa_in_b, sa_out_w, sa_out_b, proj_w, proj_b, pooled);

    cross_attn_kernel<<<dim3(16384), dim3(128), 0, stream>>>(
        pooled, ca_in_w, ca_in_b, ca_out_w, ca_out_b, ln_g, ln_b, seq);

    head_kernel<<<dim3(256), dim3(256), 0, stream>>>(
        seq, fd1_w, fd1_b, fd2_w, fd2_b, outp);
}